// Round 12
// baseline (85.270 us; speedup 1.0000x reference)
//
#include <hip/hip_runtime.h>

#define HW    (128*128)
#define DHW   (128*128*128)
#define NTOT  (4*DHW)
#define NBLK  2048         // reduce blocks: 4 batches * 16 y-tiles * 32 z-chunks(4z)

__device__ __forceinline__ float sigf(float x){ return 1.0f/(1.0f+__expf(-x)); }
__device__ __forceinline__ float4 ld4(const float* p){ return *(const float4*)p; }

// ws float layout: p_occ[NBLK], p_surf[NBLK], p_over[NBLK], p_trap[4]

// ---------------------------------------------------------------------------
// mega_k: heterogeneous grid of 4+NBLK blocks.
//   blocks 0..3   : resin-trap 16^3 box sim (one per batch), hidden under reduce.
//   blocks 4..    : occ/surface/overhang reduction, 4 z-slices per block.
// Reduce path (R12): SINGLE-BARRIER, FULL-PREFETCH. All global loads (4 val
// planes + P(z0-1) staging + 6 halo rows) are issued before one barrier;
// P planes for all 4 slices live in LDS simultaneously (4*10*132 = 5280 fl).
// Compute phase is pure register+LDS, no further barriers. (R11 had 4
// per-slice barriers serializing load->build->read chains; mega was ~22us
// vs ~6us HBM floor.)
// ---------------------------------------------------------------------------
__global__ __launch_bounds__(256, 4) void mega_k(
    const float* __restrict__ v, float* __restrict__ p_occ,
    float* __restrict__ p_surf, float* __restrict__ p_over,
    float* __restrict__ p_trap)
{
    __shared__ float4 smem4[1445];          // 5780 floats (trap needs all of it)
    __shared__ float sred[16];
    float* smem = (float*)smem4;

    const int bid = blockIdx.x;
    const int tid = threadIdx.x;
    const float4 zero4 = make_float4(0,0,0,0);

    if (bid < 4) {
        // ================= trap box path (unchanged since R10, passed) =====
        const int b = bid;
        const size_t gb = (size_t)b * DHW;
        const int ty = tid & 15, tz = tid >> 4;
        const float a_lo = sigf(-10.0f), a_hi = sigf(10.0f);
        #define M(zz,yy) (smem + (((zz)*17 + (yy))*20))

        float m[16], nv[16];
        {
            const float* rv = v + gb + ((size_t)tz*128 + ty)*128;
            int dzy = abs(tz-5) + abs(ty-5);
            #pragma unroll
            for (int q = 0; q < 4; ++q) {
                int x4 = 4*q;
                float4 a = ld4(rv + x4);
                nv[x4+0]=1.f-a.x; nv[x4+1]=1.f-a.y; nv[x4+2]=1.f-a.z; nv[x4+3]=1.f-a.w;
                int d0=dzy+abs(x4+0-5), d1=dzy+abs(x4+1-5);
                int d2=dzy+abs(x4+2-5), d3=dzy+abs(x4+3-5);
                m[x4+0] = ((d0==0)?1.f:((d0==1)?a_hi:a_lo)) * nv[x4+0];
                m[x4+1] = ((d1==0)?1.f:((d1==1)?a_hi:a_lo)) * nv[x4+1];
                m[x4+2] = ((d2==0)?1.f:((d2==1)?a_hi:a_lo)) * nv[x4+2];
                m[x4+3] = ((d3==0)?1.f:((d3==1)?a_hi:a_lo)) * nv[x4+3];
                *(float4*)(M(tz,ty) + x4) = make_float4(m[x4+0],m[x4+1],m[x4+2],m[x4+3]);
            }
        }
        const float xrE = a_lo * (1.f - v[gb + ((size_t)tz*128 + ty)*128 + 16]);
        {
            int a = tid >> 4, e = tid & 15;
            M(16,a)[e] = a_lo * (1.f - v[gb + ((size_t)16*128 + a)*128 + e]);
            M(a,16)[e] = a_lo * (1.f - v[gb + ((size_t)a*128 + 16)*128 + e]);
        }
        __syncthreads();

        for (int it = 0; it < 9; ++it) {
            const float* YM = M(tz,ty-1);
            const float* YP = M(tz,ty+1);
            const float* ZM = M(tz-1,ty);
            const float* ZP = M(tz+1,ty);
            float nm[16];
            #pragma unroll
            for (int q = 0; q < 4; ++q) {
                int x4 = 4*q;
                float4 ym = (ty > 0) ? *(const float4*)(YM + x4) : zero4;
                float4 yp = *(const float4*)(YP + x4);
                float4 zm = (tz > 0) ? *(const float4*)(ZM + x4) : zero4;
                float4 zp = *(const float4*)(ZP + x4);
                float xl = (q == 0) ? 0.f : m[x4-1];
                float xr = (q == 3) ? xrE : m[x4+4];
                float s0 = xl      + m[x4+1] + ym.x + yp.x + zm.x + zp.x;
                float s1 = m[x4+0] + m[x4+2] + ym.y + yp.y + zm.y + zp.y;
                float s2 = m[x4+1] + m[x4+3] + ym.z + yp.z + zm.z + zp.z;
                float s3 = m[x4+2] + xr      + ym.w + yp.w + zm.w + zp.w;
                nm[x4+0] = fmaxf(m[x4+0], sigf(20.f*s0 - 10.f)) * nv[x4+0];
                nm[x4+1] = fmaxf(m[x4+1], sigf(20.f*s1 - 10.f)) * nv[x4+1];
                nm[x4+2] = fmaxf(m[x4+2], sigf(20.f*s2 - 10.f)) * nv[x4+2];
                nm[x4+3] = fmaxf(m[x4+3], sigf(20.f*s3 - 10.f)) * nv[x4+3];
            }
            __syncthreads();
            float* W = M(tz,ty);
            #pragma unroll
            for (int q = 0; q < 4; ++q) {
                int x4 = 4*q;
                *(float4*)(W + x4) = make_float4(nm[x4+0],nm[x4+1],nm[x4+2],nm[x4+3]);
                m[x4+0]=nm[x4+0]; m[x4+1]=nm[x4+1]; m[x4+2]=nm[x4+2]; m[x4+3]=nm[x4+3];
            }
            __syncthreads();
        }

        float d = 0.f;
        #pragma unroll
        for (int x = 0; x < 16; ++x) d += m[x] - a_lo * nv[x];
        #pragma unroll
        for (int o = 32; o; o >>= 1) d += __shfl_down(d, o, 64);
        int lane = tid & 63, wid = tid >> 6;
        if (lane == 0) sred[wid] = d;
        __syncthreads();
        if (tid == 0) p_trap[b] = sred[0] + sred[1] + sred[2] + sred[3];
        #undef M
    } else {
        // ================= reduce path =================
        const int rid = bid - 4;                 // 0..2047
        const int b   = rid >> 9;                // batch
        const int rem = rid & 511;
        const int z0  = (rem >> 4) * 4;          // z-chunk of 4 (0..124)
        const int y0  = (rem & 15) * 8;          // y-tile of 8
        const int tx  = tid & 31, ty = tid >> 5;
        const int x4  = tx * 4;
        const int y   = y0 + ty;
        const size_t gb = (size_t)b * DHW;
        // buffer s holds P(plane z0+s-1): rows r=0..9 -> y0-1..y0+8
        #define PB(p,r) (smem + ((p)*1320 + (r)*132))

        // ---- prefetch phase: issue ALL global loads, then build P planes ----
        // own val planes z0..z0+3
        float4 vals[4];
        #pragma unroll
        for (int s = 0; s < 4; ++s)
            vals[s] = ld4(v + gb + (size_t)(z0+s)*HW + y*128 + x4);

        // P(z0-1) staging: 10 rows x 32 quads (only if z0>=1)
        if (z0 >= 1) {
            const float* bp = v + gb + (size_t)(z0-1)*HW;
            for (int i = tid; i < 320; i += 256) {
                int r = i >> 5, xq = i & 31, xi = xq*4;
                int gy = y0 - 1 + r;
                float4 q = ((unsigned)gy <= 127u) ? ld4(bp + gy*128 + xi) : zero4;
                float ql = __shfl_up(q.w, 1);   if (xq == 0)  ql = 0.f;
                float qr = __shfl_down(q.x, 1); if (xq == 31) qr = 0.f;
                *(float4*)(PB(0,r) + xi) =
                    make_float4(ql+q.x+q.y, q.x+q.y+q.z, q.y+q.z+q.w, q.z+q.w+qr);
            }
        }
        // halo rows (y0-1, y0+8) for planes z0..z0+2 -> buffers 1..3
        if (tid < 192) {
            int ps = tid >> 6;                   // 0..2 -> plane z0+ps
            int r6 = tid & 63;
            int h  = r6 >> 5, xq = r6 & 31, xi = xq*4;
            int gy = h ? (y0 + 8) : (y0 - 1);
            float4 q = ((unsigned)gy <= 127u)
                     ? ld4(v + gb + (size_t)(z0+ps)*HW + gy*128 + xi) : zero4;
            float hl = __shfl_up(q.w, 1);   if (xq == 0)  hl = 0.f;
            float hr = __shfl_down(q.x, 1); if (xq == 31) hr = 0.f;
            *(float4*)(PB(ps+1, h ? 9 : 0) + xi) =
                make_float4(hl+q.x+q.y, q.x+q.y+q.z, q.y+q.z+q.w, q.z+q.w+hr);
        }
        // interior P rows for planes z0..z0+2 from own val registers
        #pragma unroll
        for (int s = 0; s < 3; ++s) {
            float4 q = vals[s];
            float ql = __shfl_up(q.w, 1);   if (tx == 0)  ql = 0.f;
            float qr = __shfl_down(q.x, 1); if (tx == 31) qr = 0.f;
            *(float4*)(PB(s+1, ty+1) + x4) =
                make_float4(ql+q.x+q.y, q.x+q.y+q.z, q.y+q.z+q.w, q.z+q.w+qr);
        }
        __syncthreads();   // THE one barrier

        // ---- compute phase: registers + LDS only ----
        const float wy  = (y==0 || y==127) ? 2.f : 3.f;
        const float wx0 = (x4==0)   ? 2.f : 3.f;
        const float wx3 = (x4==124) ? 2.f : 3.f;
        const float inv9 = 1.f/9.f;

        float occ = 0.f, surf = 0.f, over = 0.f;
        #pragma unroll
        for (int s = 0; s < 4; ++s) {
            const int z = z0 + s;
            float4 val = vals[s];
            occ += val.x + val.y + val.z + val.w;
            float wz = (z==0 || z==127) ? 2.f : 3.f;
            surf += wz*wy*(wx0*val.x + 3.f*val.y + 3.f*val.z + wx3*val.w);
            if (z >= 1) {
                float4 a = *(const float4*)(PB(s, ty)   + x4);
                float4 c = *(const float4*)(PB(s, ty+1) + x4);
                float4 d = *(const float4*)(PB(s, ty+2) + x4);
                over += val.x*(1.f - (a.x+c.x+d.x)*inv9)
                      + val.y*(1.f - (a.y+c.y+d.y)*inv9)
                      + val.z*(1.f - (a.z+c.z+d.z)*inv9)
                      + val.w*(1.f - (a.w+c.w+d.w)*inv9);
            }
        }

        #pragma unroll
        for (int o = 32; o; o >>= 1) {
            occ  += __shfl_down(occ,  o, 64);
            surf += __shfl_down(surf, o, 64);
            over += __shfl_down(over, o, 64);
        }
        int lane = tid & 63, wid = tid >> 6;
        if (lane == 0) { sred[wid]=occ; sred[4+wid]=surf; sred[8+wid]=over; }
        __syncthreads();
        if (tid == 0) {
            p_occ [rid] = sred[0]+sred[1]+sred[2]+sred[3];
            p_surf[rid] = sred[4]+sred[5]+sred[6]+sred[7];
            p_over[rid] = sred[8]+sred[9]+sred[10]+sred[11];
        }
        #undef PB
    }
}

// ---------------------------------------------------------------------------
// finalize: sum partials (f64), combine with trap deltas.
// trap_sum = a_lo*(N - sum(v)) + sum(box deltas)
// ---------------------------------------------------------------------------
__global__ __launch_bounds__(1024) void finalize_k(
    const float* __restrict__ p_occ, const float* __restrict__ p_surf,
    const float* __restrict__ p_over, const float* __restrict__ p_trap,
    float* __restrict__ out)
{
    double occ=0, surf=0, over=0;
    for (int i = threadIdx.x; i < NBLK; i += 1024) {
        occ += p_occ[i]; surf += p_surf[i]; over += p_over[i];
    }
    __shared__ double sm[3][16];
    #pragma unroll
    for (int o = 32; o; o >>= 1) {
        occ  += __shfl_down(occ,  o, 64);
        surf += __shfl_down(surf, o, 64);
        over += __shfl_down(over, o, 64);
    }
    int lane = threadIdx.x & 63, wid = threadIdx.x >> 6;
    if (lane == 0) { sm[0][wid]=occ; sm[1][wid]=surf; sm[2][wid]=over; }
    __syncthreads();
    if (threadIdx.x == 0) {
        double so=0, ss=0, sv=0;
        for (int w = 0; w < 16; ++w) { so+=sm[0][w]; ss+=sm[1][w]; sv+=sm[2][w]; }
        double dS = (double)p_trap[0] + p_trap[1] + p_trap[2] + p_trap[3];
        double a_lo = 1.0 / (1.0 + exp(10.0));
        double N = (double)NTOT;
        double trap_sum = a_lo * (N - so) + dS;
        double occupancy = so / N;
        double occ_pen = 10.0 * (occupancy - 0.5) * (occupancy - 0.5);
        out[0] = (float)(sv / N);
        out[1] = (float)(ss / 27.0 / N - 100.0 * trap_sum / N - occ_pen);
    }
}

extern "C" void kernel_launch(void* const* d_in, const int* in_sizes, int n_in,
                              void* d_out, int out_size, void* d_ws, size_t ws_size,
                              hipStream_t stream)
{
    const float* v = (const float*)d_in[0];
    float* out = (float*)d_out;
    float* ws = (float*)d_ws;

    float* p_occ  = ws;
    float* p_surf = p_occ  + NBLK;
    float* p_over = p_surf + NBLK;
    float* p_trap = p_over + NBLK;   // 4 floats

    mega_k<<<NBLK + 4, 256, 0, stream>>>(v, p_occ, p_surf, p_over, p_trap);
    finalize_k<<<1, 1024, 0, stream>>>(p_occ, p_surf, p_over, p_trap, out);
}

// Round 14
// 84.756 us; speedup vs baseline: 1.0061x; 1.0061x over previous
//
#include <hip/hip_runtime.h>

#define HW    (128*128)
#define DHW   (128*128*128)
#define NTOT  (4*DHW)
#define NBLK  2048         // reduce blocks: 4 batches * 16 y-tiles * 32 z-chunks(4z)

__device__ __forceinline__ float sigf(float x){ return 1.0f/(1.0f+__expf(-x)); }
__device__ __forceinline__ float4 ld4(const float* p){ return *(const float4*)p; }

// ws float layout: p_occ[NBLK], p_surf[NBLK], p_over[NBLK], p_trap[4]
// R13 lesson: hipLaunchCooperativeKernel silently no-ops under this harness's
// graph capture (out never written). R7 lesson: same-address global atomics
// serialize at ~13ns/op. So: two plain dispatches, partials in ws.

// ---------------------------------------------------------------------------
// mega_k: heterogeneous grid of 4+NBLK blocks.
//   blocks 0..3   : resin-trap 16^3 box sim (one per batch), hidden under reduce.
//   blocks 4..    : occ/surface/overhang reduction, 4 z-slices per block.
// Reduce path: single barrier, full prefetch; P planes (x-windowed 3-sum of
// the below plane) for all 4 slices in LDS; compute phase is register+LDS.
// ---------------------------------------------------------------------------
__global__ __launch_bounds__(256, 4) void mega_k(
    const float* __restrict__ v, float* __restrict__ p_occ,
    float* __restrict__ p_surf, float* __restrict__ p_over,
    float* __restrict__ p_trap)
{
    __shared__ float4 smem4[1445];          // 5780 floats (trap needs all of it)
    __shared__ float sred[16];
    float* smem = (float*)smem4;

    const int bid = blockIdx.x;
    const int tid = threadIdx.x;
    const float4 zero4 = make_float4(0,0,0,0);

    if (bid < 4) {
        // ================= trap box path (unchanged since R10, passed) =====
        const int b = bid;
        const size_t gb = (size_t)b * DHW;
        const int ty = tid & 15, tz = tid >> 4;
        const float a_lo = sigf(-10.0f), a_hi = sigf(10.0f);
        #define M(zz,yy) (smem + (((zz)*17 + (yy))*20))

        float m[16], nv[16];
        {
            const float* rv = v + gb + ((size_t)tz*128 + ty)*128;
            int dzy = abs(tz-5) + abs(ty-5);
            #pragma unroll
            for (int q = 0; q < 4; ++q) {
                int x4 = 4*q;
                float4 a = ld4(rv + x4);
                nv[x4+0]=1.f-a.x; nv[x4+1]=1.f-a.y; nv[x4+2]=1.f-a.z; nv[x4+3]=1.f-a.w;
                int d0=dzy+abs(x4+0-5), d1=dzy+abs(x4+1-5);
                int d2=dzy+abs(x4+2-5), d3=dzy+abs(x4+3-5);
                m[x4+0] = ((d0==0)?1.f:((d0==1)?a_hi:a_lo)) * nv[x4+0];
                m[x4+1] = ((d1==0)?1.f:((d1==1)?a_hi:a_lo)) * nv[x4+1];
                m[x4+2] = ((d2==0)?1.f:((d2==1)?a_hi:a_lo)) * nv[x4+2];
                m[x4+3] = ((d3==0)?1.f:((d3==1)?a_hi:a_lo)) * nv[x4+3];
                *(float4*)(M(tz,ty) + x4) = make_float4(m[x4+0],m[x4+1],m[x4+2],m[x4+3]);
            }
        }
        const float xrE = a_lo * (1.f - v[gb + ((size_t)tz*128 + ty)*128 + 16]);
        {
            int a = tid >> 4, e = tid & 15;
            M(16,a)[e] = a_lo * (1.f - v[gb + ((size_t)16*128 + a)*128 + e]);
            M(a,16)[e] = a_lo * (1.f - v[gb + ((size_t)a*128 + 16)*128 + e]);
        }
        __syncthreads();

        for (int it = 0; it < 9; ++it) {
            const float* YM = M(tz,ty-1);
            const float* YP = M(tz,ty+1);
            const float* ZM = M(tz-1,ty);
            const float* ZP = M(tz+1,ty);
            float nm[16];
            #pragma unroll
            for (int q = 0; q < 4; ++q) {
                int x4 = 4*q;
                float4 ym = (ty > 0) ? *(const float4*)(YM + x4) : zero4;
                float4 yp = *(const float4*)(YP + x4);
                float4 zm = (tz > 0) ? *(const float4*)(ZM + x4) : zero4;
                float4 zp = *(const float4*)(ZP + x4);
                float xl = (q == 0) ? 0.f : m[x4-1];
                float xr = (q == 3) ? xrE : m[x4+4];
                float s0 = xl      + m[x4+1] + ym.x + yp.x + zm.x + zp.x;
                float s1 = m[x4+0] + m[x4+2] + ym.y + yp.y + zm.y + zp.y;
                float s2 = m[x4+1] + m[x4+3] + ym.z + yp.z + zm.z + zp.z;
                float s3 = m[x4+2] + xr      + ym.w + yp.w + zm.w + zp.w;
                nm[x4+0] = fmaxf(m[x4+0], sigf(20.f*s0 - 10.f)) * nv[x4+0];
                nm[x4+1] = fmaxf(m[x4+1], sigf(20.f*s1 - 10.f)) * nv[x4+1];
                nm[x4+2] = fmaxf(m[x4+2], sigf(20.f*s2 - 10.f)) * nv[x4+2];
                nm[x4+3] = fmaxf(m[x4+3], sigf(20.f*s3 - 10.f)) * nv[x4+3];
            }
            __syncthreads();
            float* W = M(tz,ty);
            #pragma unroll
            for (int q = 0; q < 4; ++q) {
                int x4 = 4*q;
                *(float4*)(W + x4) = make_float4(nm[x4+0],nm[x4+1],nm[x4+2],nm[x4+3]);
                m[x4+0]=nm[x4+0]; m[x4+1]=nm[x4+1]; m[x4+2]=nm[x4+2]; m[x4+3]=nm[x4+3];
            }
            __syncthreads();
        }

        float d = 0.f;
        #pragma unroll
        for (int x = 0; x < 16; ++x) d += m[x] - a_lo * nv[x];
        #pragma unroll
        for (int o = 32; o; o >>= 1) d += __shfl_down(d, o, 64);
        int lane = tid & 63, wid = tid >> 6;
        if (lane == 0) sred[wid] = d;
        __syncthreads();
        if (tid == 0) p_trap[b] = sred[0] + sred[1] + sred[2] + sred[3];
        #undef M
    } else {
        // ================= reduce path =================
        const int rid = bid - 4;                 // 0..2047
        const int b   = rid >> 9;                // batch
        const int rem = rid & 511;
        const int z0  = (rem >> 4) * 4;          // z-chunk of 4 (0..124)
        const int y0  = (rem & 15) * 8;          // y-tile of 8
        const int tx  = tid & 31, ty = tid >> 5;
        const int x4  = tx * 4;
        const int y   = y0 + ty;
        const size_t gb = (size_t)b * DHW;
        #define PB(p,r) (smem + ((p)*1320 + (r)*132))

        float4 vals[4];
        #pragma unroll
        for (int s = 0; s < 4; ++s)
            vals[s] = ld4(v + gb + (size_t)(z0+s)*HW + y*128 + x4);

        if (z0 >= 1) {
            const float* bp = v + gb + (size_t)(z0-1)*HW;
            for (int i = tid; i < 320; i += 256) {
                int r = i >> 5, xq = i & 31, xi = xq*4;
                int gy = y0 - 1 + r;
                float4 q = ((unsigned)gy <= 127u) ? ld4(bp + gy*128 + xi) : zero4;
                float ql = __shfl_up(q.w, 1);   if (xq == 0)  ql = 0.f;
                float qr = __shfl_down(q.x, 1); if (xq == 31) qr = 0.f;
                *(float4*)(PB(0,r) + xi) =
                    make_float4(ql+q.x+q.y, q.x+q.y+q.z, q.y+q.z+q.w, q.z+q.w+qr);
            }
        }
        if (tid < 192) {
            int ps = tid >> 6;                   // 0..2 -> plane z0+ps
            int r6 = tid & 63;
            int h  = r6 >> 5, xq = r6 & 31, xi = xq*4;
            int gy = h ? (y0 + 8) : (y0 - 1);
            float4 q = ((unsigned)gy <= 127u)
                     ? ld4(v + gb + (size_t)(z0+ps)*HW + gy*128 + xi) : zero4;
            float hl = __shfl_up(q.w, 1);   if (xq == 0)  hl = 0.f;
            float hr = __shfl_down(q.x, 1); if (xq == 31) hr = 0.f;
            *(float4*)(PB(ps+1, h ? 9 : 0) + xi) =
                make_float4(hl+q.x+q.y, q.x+q.y+q.z, q.y+q.z+q.w, q.z+q.w+hr);
        }
        #pragma unroll
        for (int s = 0; s < 3; ++s) {
            float4 q = vals[s];
            float ql = __shfl_up(q.w, 1);   if (tx == 0)  ql = 0.f;
            float qr = __shfl_down(q.x, 1); if (tx == 31) qr = 0.f;
            *(float4*)(PB(s+1, ty+1) + x4) =
                make_float4(ql+q.x+q.y, q.x+q.y+q.z, q.y+q.z+q.w, q.z+q.w+qr);
        }
        __syncthreads();   // the one barrier

        const float wy  = (y==0 || y==127) ? 2.f : 3.f;
        const float wx0 = (x4==0)   ? 2.f : 3.f;
        const float wx3 = (x4==124) ? 2.f : 3.f;
        const float inv9 = 1.f/9.f;

        float occ = 0.f, surf = 0.f, over = 0.f;
        #pragma unroll
        for (int s = 0; s < 4; ++s) {
            const int z = z0 + s;
            float4 val = vals[s];
            occ += val.x + val.y + val.z + val.w;
            float wz = (z==0 || z==127) ? 2.f : 3.f;
            surf += wz*wy*(wx0*val.x + 3.f*val.y + 3.f*val.z + wx3*val.w);
            if (z >= 1) {
                float4 a = *(const float4*)(PB(s, ty)   + x4);
                float4 c = *(const float4*)(PB(s, ty+1) + x4);
                float4 d = *(const float4*)(PB(s, ty+2) + x4);
                over += val.x*(1.f - (a.x+c.x+d.x)*inv9)
                      + val.y*(1.f - (a.y+c.y+d.y)*inv9)
                      + val.z*(1.f - (a.z+c.z+d.z)*inv9)
                      + val.w*(1.f - (a.w+c.w+d.w)*inv9);
            }
        }

        #pragma unroll
        for (int o = 32; o; o >>= 1) {
            occ  += __shfl_down(occ,  o, 64);
            surf += __shfl_down(surf, o, 64);
            over += __shfl_down(over, o, 64);
        }
        int lane = tid & 63, wid = tid >> 6;
        if (lane == 0) { sred[wid]=occ; sred[4+wid]=surf; sred[8+wid]=over; }
        __syncthreads();
        if (tid == 0) {
            p_occ [rid] = sred[0]+sred[1]+sred[2]+sred[3];
            p_surf[rid] = sred[4]+sred[5]+sred[6]+sred[7];
            p_over[rid] = sred[8]+sred[9]+sred[10]+sred[11];
        }
        #undef PB
    }
}

// ---------------------------------------------------------------------------
// finalize: sum partials (f64), combine with trap deltas.
// trap_sum = a_lo*(N - sum(v)) + sum(box deltas)
// ---------------------------------------------------------------------------
__global__ __launch_bounds__(1024) void finalize_k(
    const float* __restrict__ p_occ, const float* __restrict__ p_surf,
    const float* __restrict__ p_over, const float* __restrict__ p_trap,
    float* __restrict__ out)
{
    double occ=0, surf=0, over=0;
    for (int i = threadIdx.x; i < NBLK; i += 1024) {
        occ += p_occ[i]; surf += p_surf[i]; over += p_over[i];
    }
    __shared__ double sm[3][16];
    #pragma unroll
    for (int o = 32; o; o >>= 1) {
        occ  += __shfl_down(occ,  o, 64);
        surf += __shfl_down(surf, o, 64);
        over += __shfl_down(over, o, 64);
    }
    int lane = threadIdx.x & 63, wid = threadIdx.x >> 6;
    if (lane == 0) { sm[0][wid]=occ; sm[1][wid]=surf; sm[2][wid]=over; }
    __syncthreads();
    if (threadIdx.x == 0) {
        double so=0, ss=0, sv=0;
        for (int w = 0; w < 16; ++w) { so+=sm[0][w]; ss+=sm[1][w]; sv+=sm[2][w]; }
        double dS = (double)p_trap[0] + p_trap[1] + p_trap[2] + p_trap[3];
        double a_lo = 1.0 / (1.0 + exp(10.0));
        double N = (double)NTOT;
        double trap_sum = a_lo * (N - so) + dS;
        double occupancy = so / N;
        double occ_pen = 10.0 * (occupancy - 0.5) * (occupancy - 0.5);
        out[0] = (float)(sv / N);
        out[1] = (float)(ss / 27.0 / N - 100.0 * trap_sum / N - occ_pen);
    }
}

extern "C" void kernel_launch(void* const* d_in, const int* in_sizes, int n_in,
                              void* d_out, int out_size, void* d_ws, size_t ws_size,
                              hipStream_t stream)
{
    const float* v = (const float*)d_in[0];
    float* out = (float*)d_out;
    float* ws = (float*)d_ws;

    float* p_occ  = ws;
    float* p_surf = p_occ  + NBLK;
    float* p_over = p_surf + NBLK;
    float* p_trap = p_over + NBLK;   // 4 floats

    mega_k<<<NBLK + 4, 256, 0, stream>>>(v, p_occ, p_surf, p_over, p_trap);
    finalize_k<<<1, 1024, 0, stream>>>(p_occ, p_surf, p_over, p_trap, out);
}